// Round 9
// baseline (228.905 us; speedup 1.0000x reference)
//
#include <hip/hip_runtime.h>

// ---------------------------------------------------------------------------
// Res_up block, round 9: round 8 + interp fused into agg (P/Q/U interpolated
// on the fly from L2-resident coarse GEMM results; PQf buffer eliminated).
// 10 dispatches.
// Sizes fixed: Nc=4096, Nf=16384, Ec=65536, Ef=262144, Cin=128, Ch=64, Co=128.
// ---------------------------------------------------------------------------

#define SELU_SCALE 1.0507009873554805f
#define SELU_ALPHA 1.6732632423543772f

static constexpr int NC = 4096, NF = 16384, EC = 65536, EF = 262144;
static constexpr int G = 32, NCELL = G * G;

typedef __attribute__((ext_vector_type(8))) short short8v;
typedef __attribute__((ext_vector_type(4))) float f32x4;
typedef unsigned short ushort_t;
typedef unsigned long long u64;

__device__ __forceinline__ float selu_f(float x) {
    return x > 0.0f ? SELU_SCALE * x
                    : SELU_SCALE * SELU_ALPHA * (__expf(x) - 1.0f);
}
__device__ __forceinline__ ushort_t f2bf(float f) {
    unsigned u = __float_as_uint(f);
    u += 0x7FFFu + ((u >> 16) & 1u);
    return (ushort_t)(u >> 16);
}
__device__ __forceinline__ float bf2f(ushort_t u) {
    return __uint_as_float(((unsigned)u) << 16);
}
__device__ __forceinline__ int cell_of(float2 p) {
    int cx = (int)(p.x * (float)G); cx = cx > G - 1 ? G - 1 : cx;
    int cy = (int)(p.y * (float)G); cy = cy > G - 1 ? G - 1 : cy;
    return cy * G + cx;
}
__device__ __forceinline__ void ins3(u64& a0, u64& a1, u64& a2, u64 v) {
    if (v < a2) {
        if (v < a1) {
            a2 = a1;
            if (v < a0) { a1 = a0; a0 = v; } else a1 = v;
        } else a2 = v;
    }
}

// ---------------------------------------------------------------------------
// Fragment-major weight writer: Wf[(ntile*KC+kc)*512 + lane*8 + e] = W[k][col]
// ---------------------------------------------------------------------------
template <int K, typename F>
__device__ __forceinline__ void wfrag(F getw, ushort_t* __restrict__ dst, int idx) {
    constexpr int KC = K / 32;
    const int f = idx >> 9;
    const int r = idx & 511;
    const int lane = r >> 3;
    const int e = r & 7;
    const int ntile = f / KC;
    const int kc = f - ntile * KC;
    const int k = kc * 32 + ((lane >> 4) << 3) + e;
    const int col = ntile * 16 + (lane & 15);
    dst[idx] = f2bf(getw(k, col));
}

// ---------------------------------------------------------------------------
// prep: x->bf16, 5 weight-frag buffers, zero cnt/stats.
// ---------------------------------------------------------------------------
__global__ __launch_bounds__(256) void prep_kernel(
    const float* __restrict__ x, ushort_t* __restrict__ xb,
    const float* __restrict__ WeS, const float* __restrict__ WnS,
    const float* __restrict__ We1, const float* __restrict__ We2,
    const float* __restrict__ Wn2, const float* __restrict__ Wn1,
    ushort_t* __restrict__ WfA, ushort_t* __restrict__ WfE,
    ushort_t* __restrict__ WfSn, ushort_t* __restrict__ Wf1n,
    ushort_t* __restrict__ Wf2n,
    int* __restrict__ cntF, int* __restrict__ cntC, int* __restrict__ cntG,
    float* __restrict__ stats) {
    int i = blockIdx.x * 256 + threadIdx.x;
    if (i < NC * 128) { xb[i] = f2bf(x[i]); return; }
    i -= NC * 128;
    if (i < 65536) {   // RA weights: K=128, N=512
        wfrag<128>([&](int k, int j) {
            return j < 128 ? WeS[k * 128 + j]
                 : j < 256 ? WeS[(128 + k) * 128 + (j - 128)]
                 : j < 384 ? WnS[k * 128 + (j - 256)]
                 : j < 448 ? We1[k * 64 + (j - 384)]
                           : We1[(128 + k) * 64 + (j - 448)];
        }, WfA, i);
        return;
    }
    i -= 65536;
    if (i < 24576) {   // RE weights: K=64, N=384
        wfrag<64>([&](int k, int j) {
            return j < 128 ? We2[k * 128 + j]
                 : j < 256 ? We2[(64 + k) * 128 + (j - 128)]
                           : Wn2[k * 128 + (j - 256)];
        }, WfE, i);
        return;
    }
    i -= 24576;
    if (i < 16384) {   // nodeS: WnS bottom half, K=128, N=128
        wfrag<128>([&](int k, int j) { return WnS[(128 + k) * 128 + j]; }, WfSn, i);
        return;
    }
    i -= 16384;
    if (i < 12288) {   // node1: full Wn1, K=192, N=64
        wfrag<192>([&](int k, int j) { return Wn1[k * 64 + j]; }, Wf1n, i);
        return;
    }
    i -= 12288;
    if (i < 16384) {   // nodeH: Wn2 bottom, K=128, N=128
        wfrag<128>([&](int k, int j) { return Wn2[(64 + k) * 128 + j]; }, Wf2n, i);
        return;
    }
    i -= 16384;
    if (i < NF) { cntF[i] = 0; return; }
    i -= NF;
    if (i < NC) { cntC[i] = 0; return; }
    i -= NC;
    if (i < NCELL) { cntG[i] = 0; return; }
    i -= NCELL;
    if (i < 256) { stats[i] = 0.0f; return; }
}

// ---------------------------------------------------------------------------
// merged histogram / scan / scatter for {fine edges, coarse edges, grid cells}
// ---------------------------------------------------------------------------
__global__ __launch_bounds__(256) void hist3_kernel(
    const int* __restrict__ ei_f, const int* __restrict__ ei_c,
    const float* __restrict__ pos_c,
    int* __restrict__ cntF, int* __restrict__ cntC, int* __restrict__ cntG) {
    int i = blockIdx.x * 256 + threadIdx.x;
    if (i < EF) { atomicAdd(&cntF[ei_f[EF + i]], 1); return; }
    i -= EF;
    if (i < EC) { atomicAdd(&cntC[ei_c[EC + i]], 1); return; }
    i -= EC;
    if (i < NC) {
        float2 p = ((const float2*)pos_c)[i];
        atomicAdd(&cntG[cell_of(p)], 1);
    }
}

__global__ __launch_bounds__(1024) void scan3_kernel(
    int* __restrict__ cntF, int* __restrict__ baseF, int* __restrict__ cursF,
    int* __restrict__ cntC, int* __restrict__ baseC, int* __restrict__ cursC,
    int* __restrict__ cntG, int* __restrict__ baseG, int* __restrict__ cursG) {
    const int* cnt; int* base; int* curs; int n;
    if (blockIdx.x == 0)      { cnt = cntF; base = baseF; curs = cursF; n = NF; }
    else if (blockIdx.x == 1) { cnt = cntC; base = baseC; curs = cursC; n = NC; }
    else                      { cnt = cntG; base = baseG; curs = cursG; n = NCELL; }
    const int IT = n >> 10;
    __shared__ int part[1024];
    const int t = threadIdx.x;
    int loc[16];
    int s = 0;
#pragma unroll
    for (int i = 0; i < 16; ++i) {
        int v = (i < IT) ? cnt[t * IT + i] : 0;
        loc[i] = v; s += v;
    }
    part[t] = s;
    __syncthreads();
    for (int off = 1; off < 1024; off <<= 1) {
        int v = part[t];
        int u = (t >= off) ? part[t - off] : 0;
        __syncthreads();
        part[t] = v + u;
        __syncthreads();
    }
    int ex = (t == 0) ? 0 : part[t - 1];
#pragma unroll
    for (int i = 0; i < 16; ++i) {
        if (i < IT) {
            base[t * IT + i] = ex;
            curs[t * IT + i] = ex;
            ex += loc[i];
        }
    }
    if (t == 1023) base[n] = ex;
}

__global__ __launch_bounds__(256) void scatter3_kernel(
    const int* __restrict__ ei_f, const int* __restrict__ ei_c,
    const float* __restrict__ pos_c,
    int* __restrict__ cursF, int* __restrict__ srtF,
    int* __restrict__ cursC, int* __restrict__ srtC,
    int* __restrict__ cursG, float4* __restrict__ grecs) {
    int i = blockIdx.x * 256 + threadIdx.x;
    if (i < EF) {
        int pos = atomicAdd(&cursF[ei_f[EF + i]], 1);
        srtF[pos] = ei_f[i];
        return;
    }
    i -= EF;
    if (i < EC) {
        int pos = atomicAdd(&cursC[ei_c[EC + i]], 1);
        srtC[pos] = ei_c[i];
        return;
    }
    i -= EC;
    if (i < NC) {
        float2 p = ((const float2*)pos_c)[i];
        int pos = atomicAdd(&cursG[cell_of(p)], 1);
        float4 rec;
        rec.x = p.x; rec.y = p.y; rec.z = __int_as_float(i); rec.w = 0.0f;
        grecs[pos] = rec;
    }
}

// ---------------------------------------------------------------------------
// Fused: blocks 0..255 = RA GEMM (4096x512x128, bf16 out);
// blocks 256..767 = grid-kNN, 8 lanes per fine point. Meta as int4/float4.
// ---------------------------------------------------------------------------
__global__ __launch_bounds__(256) void gemmA_knn_kernel(
    const ushort_t* __restrict__ xb, const ushort_t* __restrict__ WfA,
    ushort_t* __restrict__ RA,
    const float* __restrict__ pos_f, const float4* __restrict__ grecs,
    const int* __restrict__ baseG,
    int4* __restrict__ knn_idx, float4* __restrict__ knn_w) {
    const int bid = blockIdx.x;
    const int tid = threadIdx.x;
    if (bid < 256) {
        const int wid = tid >> 6, lane = tid & 63;
        const int bx = bid >> 2, by = bid & 3;
        const int row_base = bx * 64 + wid * 16;
        const int row_a = row_base + (lane & 15);
        const int klane = (lane >> 4) << 3;
        short8v a[4];
#pragma unroll
        for (int f = 0; f < 4; ++f)
            a[f] = *(const short8v*)(xb + (size_t)row_a * 128 + f * 32 + klane);
#pragma unroll
        for (int nt = 0; nt < 8; ++nt) {
            const int ntg = by * 8 + nt;
            f32x4 acc = {0.0f, 0.0f, 0.0f, 0.0f};
#pragma unroll
            for (int f = 0; f < 4; ++f) {
                const short8v b =
                    *(const short8v*)(WfA + (size_t)(ntg * 4 + f) * 512 + lane * 8);
                acc = __builtin_amdgcn_mfma_f32_16x16x32_bf16(a[f], b, acc, 0, 0, 0);
            }
            const int col = ntg * 16 + (lane & 15);
            const int r0 = row_base + ((lane >> 4) << 2);
#pragma unroll
            for (int r = 0; r < 4; ++r)
                RA[(size_t)(r0 + r) * 512 + col] = f2bf(acc[r]);
        }
    } else {
        const int g8 = (bid - 256) * 256 + tid;    // 131072 = 8 * NF
        const int t = g8 >> 3;
        const int sub = g8 & 7;
        const float2 p = ((const float2*)pos_f)[t];
        int cx = (int)(p.x * (float)G); cx = cx > G - 1 ? G - 1 : cx;
        int cy = (int)(p.y * (float)G); cy = cy > G - 1 ? G - 1 : cy;
        const float h = 1.0f / (float)G;

        u64 b0 = ~0ull, b1 = ~0ull, b2 = ~0ull;

        {
            const int xx0 = cx - 1 < 0 ? 0 : cx - 1;
            const int xx1 = cx + 1 > G - 1 ? G - 1 : cx + 1;
            const int yy0 = cy - 1 < 0 ? 0 : cy - 1;
            const int yy1 = cy + 1 > G - 1 ? G - 1 : cy + 1;
            int rs[3], rl[3];
            int nr = 0;
            for (int yy = yy0; yy <= yy1; ++yy) {
                const int s = baseG[yy * G + xx0];
                const int e = baseG[yy * G + xx1 + 1];
                rs[nr] = s; rl[nr] = e - s; ++nr;
            }
            const int l0 = rl[0];
            const int l01 = l0 + (nr > 1 ? rl[1] : 0);
            const int m = l01 + (nr > 2 ? rl[2] : 0);
            for (int j = sub; j < m; j += 8) {
                int i;
                if (j < l0) i = rs[0] + j;
                else if (j < l01) i = rs[1] + (j - l0);
                else i = rs[2] + (j - l01);
                const float4 q = grecs[i];
                const float dx = p.x - q.x;
                const float dy = p.y - q.y;
                const float d = dx * dx + dy * dy;
                ins3(b0, b1, b2, ((u64)__float_as_uint(d) << 32) |
                                 (u64)__float_as_uint(q.z));
            }
#pragma unroll
            for (int mk = 1; mk <= 4; mk <<= 1) {
                const u64 e0 = __shfl_xor(b0, mk);
                const u64 e1 = __shfl_xor(b1, mk);
                const u64 e2 = __shfl_xor(b2, mk);
                ins3(b0, b1, b2, e0);
                ins3(b0, b1, b2, e1);
                ins3(b0, b1, b2, e2);
            }
        }

        for (int r = 2; r < G; ++r) {
            const float bd = __uint_as_float((unsigned)(b2 >> 32));
            const float lim = (float)(r - 1) * h;
            if (bd < lim * lim) break;
            u64 c0 = ~0ull, c1 = ~0ull, c2 = ~0ull;
            auto scan_cells = [&](int cell0, int cell1, int step) {
                for (int c = cell0; c <= cell1; c += step) {
                    const int s0 = baseG[c], s1 = baseG[c + 1];
                    for (int i = s0; i < s1; ++i) {
                        const float4 q = grecs[i];
                        const float dx = p.x - q.x;
                        const float dy = p.y - q.y;
                        const float d = dx * dx + dy * dy;
                        ins3(c0, c1, c2, ((u64)__float_as_uint(d) << 32) |
                                         (u64)__float_as_uint(q.z));
                    }
                }
            };
            const int side = sub & 3, phase = sub >> 2;
            const int x0 = cx - r < 0 ? 0 : cx - r;
            const int x1 = cx + r > G - 1 ? G - 1 : cx + r;
            const int yi0 = cy - r + 1 < 0 ? 0 : cy - r + 1;
            const int yi1 = cy + r - 1 > G - 1 ? G - 1 : cy + r - 1;
            if (side == 0) {
                if (cy - r >= 0) scan_cells((cy - r) * G + x0 + phase, (cy - r) * G + x1, 2);
            } else if (side == 1) {
                if (cy + r <= G - 1) scan_cells((cy + r) * G + x0 + phase, (cy + r) * G + x1, 2);
            } else if (side == 2) {
                if (cx - r >= 0 && yi0 + phase <= yi1)
                    scan_cells((yi0 + phase) * G + cx - r, yi1 * G + cx - r, 2 * G);
            } else {
                if (cx + r <= G - 1 && yi0 + phase <= yi1)
                    scan_cells((yi0 + phase) * G + cx + r, yi1 * G + cx + r, 2 * G);
            }
#pragma unroll
            for (int mk = 1; mk <= 4; mk <<= 1) {
                const u64 e0 = __shfl_xor(c0, mk);
                const u64 e1 = __shfl_xor(c1, mk);
                const u64 e2 = __shfl_xor(c2, mk);
                ins3(c0, c1, c2, e0);
                ins3(c0, c1, c2, e1);
                ins3(c0, c1, c2, e2);
            }
            ins3(b0, b1, b2, c0);
            ins3(b0, b1, b2, c1);
            ins3(b0, b1, b2, c2);
        }

        if (sub == 0) {
            const float d0 = __uint_as_float((unsigned)(b0 >> 32));
            const float d1 = __uint_as_float((unsigned)(b1 >> 32));
            const float d2 = __uint_as_float((unsigned)(b2 >> 32));
            const float w0 = 1.0f / fmaxf(d0, 1e-16f);
            const float w1 = 1.0f / fmaxf(d1, 1e-16f);
            const float w2 = 1.0f / fmaxf(d2, 1e-16f);
            const float s = 1.0f / (w0 + w1 + w2);
            int4 mi;
            mi.x = (int)(b0 & 0xffffffffu);
            mi.y = (int)(b1 & 0xffffffffu);
            mi.z = (int)(b2 & 0xffffffffu);
            mi.w = 0;
            float4 mw;
            mw.x = w0 * s; mw.y = w1 * s; mw.z = w2 * s; mw.w = 0.0f;
            knn_idx[t] = mi;
            knn_w[t] = mw;
        }
    }
}

// ---------------------------------------------------------------------------
// agg with fused interp: one wave per dst node n.
//   Qf[n] = sum_k w_k * R[i_k][Q cols] + be   (computed once)
//   Uf[n] = sum_k w_k * R[i_k][U cols]        (written out bf16)
//   agg[n] = sum_{e} selu( sum_k sw_k * R[si_k][P cols] + Qf )
// R layout: P at 0..127, Q at 128..255, U at 256..383 (bf16, row stride STRIDE)
// DUAL adds coarse agg1 blocks (RA cols 384..511, no interp).
// ---------------------------------------------------------------------------
template <int STRIDE, bool DUAL>
__global__ __launch_bounds__(256) void agg_kernel(
    const ushort_t* __restrict__ R, const int4* __restrict__ knn_idx,
    const float4* __restrict__ knn_w, const int* __restrict__ baseF,
    const int* __restrict__ srtF, const float* __restrict__ beF,
    ushort_t* __restrict__ aggF, ushort_t* __restrict__ Uf,
    const int* __restrict__ baseC, const int* __restrict__ srtC,
    const float* __restrict__ beC, ushort_t* __restrict__ aggC) {
    const int bid = blockIdx.x;
    const int wid = threadIdx.x >> 6, lane = threadIdx.x & 63;
    if (!DUAL || bid < NF / 4) {
        const int n = bid * 4 + wid;
        const int4 mi = knn_idx[n];
        const float4 mw = knn_w[n];
        const ushort_t* r0 = R + (size_t)mi.x * STRIDE + lane * 2;
        const ushort_t* r1 = R + (size_t)mi.y * STRIDE + lane * 2;
        const ushort_t* r2 = R + (size_t)mi.z * STRIDE + lane * 2;
        // Q interp (cols 128..255) + bias
        const float2 bv = *(const float2*)(beF + lane * 2);
        ushort2 a0 = *(const ushort2*)(r0 + 128);
        ushort2 a1 = *(const ushort2*)(r1 + 128);
        ushort2 a2 = *(const ushort2*)(r2 + 128);
        const float qx = mw.x * bf2f(a0.x) + mw.y * bf2f(a1.x) + mw.z * bf2f(a2.x) + bv.x;
        const float qy = mw.x * bf2f(a0.y) + mw.y * bf2f(a1.y) + mw.z * bf2f(a2.y) + bv.y;
        // U interp (cols 256..383) -> Uf
        a0 = *(const ushort2*)(r0 + 256);
        a1 = *(const ushort2*)(r1 + 256);
        a2 = *(const ushort2*)(r2 + 256);
        ushort2 uo;
        uo.x = f2bf(mw.x * bf2f(a0.x) + mw.y * bf2f(a1.x) + mw.z * bf2f(a2.x));
        uo.y = f2bf(mw.x * bf2f(a0.y) + mw.y * bf2f(a1.y) + mw.z * bf2f(a2.y));
        *(ushort2*)(Uf + (size_t)n * 128 + lane * 2) = uo;
        // edge loop: P interp per edge (cols 0..127)
        const int b0 = baseF[n], b1 = baseF[n + 1];
        float ax = 0.0f, ay = 0.0f;
        for (int e = b0; e < b1; ++e) {
            const int src = srtF[e];
            const int4 si = knn_idx[src];
            const float4 sw = knn_w[src];
            const ushort2 p0 = *(const ushort2*)(R + (size_t)si.x * STRIDE + lane * 2);
            const ushort2 p1 = *(const ushort2*)(R + (size_t)si.y * STRIDE + lane * 2);
            const ushort2 p2 = *(const ushort2*)(R + (size_t)si.z * STRIDE + lane * 2);
            const float px = sw.x * bf2f(p0.x) + sw.y * bf2f(p1.x) + sw.z * bf2f(p2.x);
            const float py = sw.x * bf2f(p0.y) + sw.y * bf2f(p1.y) + sw.z * bf2f(p2.y);
            ax += selu_f(px + qx);
            ay += selu_f(py + qy);
        }
        ushort2 r; r.x = f2bf(ax); r.y = f2bf(ay);
        *(ushort2*)(aggF + (size_t)n * 128 + lane * 2) = r;
    } else {
        const int n = (bid - NF / 4) * 4 + wid;
        const int b0 = baseC[n], b1 = baseC[n + 1];
        const float q = bf2f(R[(size_t)n * 512 + 448 + lane]) + beC[lane];
        float s = 0.0f;
        for (int e = b0; e < b1; ++e) {
            const int src = srtC[e];
            s += selu_f(bf2f(R[(size_t)src * 512 + 384 + lane]) + q);
        }
        aggC[(size_t)n * 64 + lane] = f2bf(s);
    }
}

// ---------------------------------------------------------------------------
// nodeSD: blocks 0..255: x_skip = selu(aggF@WnS_bot + UfS + bnS) -> outp f32
//         blocks 256..319: h1 = selu(concat(xb,agg1b)@Wn1 + bn1) in LDS,
//                          then RE = h1 @ WfE (fused gemmE) -> RE bf16
// ---------------------------------------------------------------------------
__global__ __launch_bounds__(256) void nodeSD_kernel(
    const ushort_t* __restrict__ aggF, const ushort_t* __restrict__ WfSn,
    const float* __restrict__ bnS, const ushort_t* __restrict__ UfS,
    float* __restrict__ outp,
    const ushort_t* __restrict__ xb, const ushort_t* __restrict__ agg1b,
    const ushort_t* __restrict__ Wf1n, const float* __restrict__ bn1,
    const ushort_t* __restrict__ WfE, ushort_t* __restrict__ RE) {
    __shared__ ushort_t h1s[64][72];
    const int tid = threadIdx.x;
    const int wid = tid >> 6, lane = tid & 63;
    const int klane = (lane >> 4) << 3;
    if (blockIdx.x < 256) {
        const int row_base = blockIdx.x * 64 + wid * 16;
        const int row_a = row_base + (lane & 15);
        short8v a[4];
#pragma unroll
        for (int f = 0; f < 4; ++f)
            a[f] = *(const short8v*)(aggF + (size_t)row_a * 128 + f * 32 + klane);
#pragma unroll
        for (int nt = 0; nt < 8; ++nt) {
            f32x4 acc = {0.0f, 0.0f, 0.0f, 0.0f};
#pragma unroll
            for (int f = 0; f < 4; ++f) {
                const short8v b =
                    *(const short8v*)(WfSn + (size_t)(nt * 4 + f) * 512 + lane * 8);
                acc = __builtin_amdgcn_mfma_f32_16x16x32_bf16(a[f], b, acc, 0, 0, 0);
            }
            const int col = nt * 16 + (lane & 15);
            const int r0 = row_base + ((lane >> 4) << 2);
#pragma unroll
            for (int r = 0; r < 4; ++r) {
                const size_t o = (size_t)(r0 + r) * 128 + col;
                outp[o] = selu_f(acc[r] + bnS[col] + bf2f(UfS[o]));
            }
        }
    } else {
        const int row_base = (blockIdx.x - 256) * 64 + wid * 16;
        const int row_a = row_base + (lane & 15);
        short8v a[6];
#pragma unroll
        for (int f = 0; f < 4; ++f)
            a[f] = *(const short8v*)(xb + (size_t)row_a * 128 + f * 32 + klane);
#pragma unroll
        for (int f = 0; f < 2; ++f)
            a[4 + f] = *(const short8v*)(agg1b + (size_t)row_a * 64 + f * 32 + klane);
#pragma unroll
        for (int nt = 0; nt < 4; ++nt) {
            f32x4 acc = {0.0f, 0.0f, 0.0f, 0.0f};
#pragma unroll
            for (int f = 0; f < 6; ++f) {
                const short8v b =
                    *(const short8v*)(Wf1n + (size_t)(nt * 6 + f) * 512 + lane * 8);
                acc = __builtin_amdgcn_mfma_f32_16x16x32_bf16(a[f], b, acc, 0, 0, 0);
            }
            const int col = nt * 16 + (lane & 15);
            const int lr0 = wid * 16 + ((lane >> 4) << 2);
#pragma unroll
            for (int r = 0; r < 4; ++r)
                h1s[lr0 + r][col] = f2bf(selu_f(acc[r] + bn1[col]));
        }
        __syncthreads();
        short8v ha[2];
#pragma unroll
        for (int f = 0; f < 2; ++f)
            ha[f] = *(const short8v*)&h1s[wid * 16 + (lane & 15)][f * 32 + klane];
#pragma unroll
        for (int nt = 0; nt < 24; ++nt) {
            f32x4 acc = {0.0f, 0.0f, 0.0f, 0.0f};
#pragma unroll
            for (int f = 0; f < 2; ++f) {
                const short8v b =
                    *(const short8v*)(WfE + (size_t)(nt * 2 + f) * 512 + lane * 8);
                acc = __builtin_amdgcn_mfma_f32_16x16x32_bf16(ha[f], b, acc, 0, 0, 0);
            }
            const int col = nt * 16 + (lane & 15);
            const int r0 = row_base + ((lane >> 4) << 2);
#pragma unroll
            for (int r = 0; r < 4; ++r)
                RE[(size_t)(r0 + r) * 384 + col] = f2bf(acc[r]);
        }
    }
}

// ---------------------------------------------------------------------------
// nodeH: v = selu(aggF@Wn2_bot + Uf2 + bn2) + x_skip; write outp; BN stats.
// ---------------------------------------------------------------------------
__global__ __launch_bounds__(256) void nodeH_kernel(
    const ushort_t* __restrict__ aggF, const ushort_t* __restrict__ Wf2n,
    const float* __restrict__ bn2, const ushort_t* __restrict__ Uf2,
    float* __restrict__ outp, float* __restrict__ stats) {
    __shared__ float s_sum[128], s_sq[128];
    const int tid = threadIdx.x;
    const int wid = tid >> 6, lane = tid & 63;
    const int klane = (lane >> 4) << 3;
    if (tid < 128) { s_sum[tid] = 0.0f; s_sq[tid] = 0.0f; }
    __syncthreads();
    const int row_base = blockIdx.x * 64 + wid * 16;
    const int row_a = row_base + (lane & 15);
    short8v a[4];
#pragma unroll
    for (int f = 0; f < 4; ++f)
        a[f] = *(const short8v*)(aggF + (size_t)row_a * 128 + f * 32 + klane);
#pragma unroll
    for (int nt = 0; nt < 8; ++nt) {
        f32x4 acc = {0.0f, 0.0f, 0.0f, 0.0f};
#pragma unroll
        for (int f = 0; f < 4; ++f) {
            const short8v b =
                *(const short8v*)(Wf2n + (size_t)(nt * 4 + f) * 512 + lane * 8);
            acc = __builtin_amdgcn_mfma_f32_16x16x32_bf16(a[f], b, acc, 0, 0, 0);
        }
        const int col = nt * 16 + (lane & 15);
        const int r0 = row_base + ((lane >> 4) << 2);
        float lsum = 0.0f, lsq = 0.0f;
#pragma unroll
        for (int r = 0; r < 4; ++r) {
            const size_t o = (size_t)(r0 + r) * 128 + col;
            float v = selu_f(acc[r] + bn2[col] + bf2f(Uf2[o])) + outp[o];
            outp[o] = v;
            lsum += v; lsq += v * v;
        }
        atomicAdd(&s_sum[nt * 16 + (lane & 15)], lsum);
        atomicAdd(&s_sq[nt * 16 + (lane & 15)], lsq);
    }
    __syncthreads();
    if (tid < 128) {
        atomicAdd(&stats[tid], s_sum[tid]);
        atomicAdd(&stats[128 + tid], s_sq[tid]);
    }
}

// ---------------------------------------------------------------------------
// BN normalize + SELU, in place on d_out.
// ---------------------------------------------------------------------------
__global__ __launch_bounds__(256) void bn_kernel(
    float* __restrict__ out, const float* __restrict__ stats,
    const float* __restrict__ gamma, const float* __restrict__ beta, int Nn) {
    const int i = blockIdx.x * blockDim.x + threadIdx.x;
    const int c = i & 127;
    const float invn = 1.0f / (float)Nn;
    float mu = stats[c] * invn;
    float var = stats[128 + c] * invn - mu * mu;
    float r = rsqrtf(var + 1e-5f);
    float v = (out[i] - mu) * r * gamma[c] + beta[c];
    out[i] = selu_f(v);
}

// ---------------------------------------------------------------------------
extern "C" void kernel_launch(void* const* d_in, const int* in_sizes, int n_in,
                              void* d_out, int out_size, void* d_ws, size_t ws_size,
                              hipStream_t stream) {
    const float* x     = (const float*)d_in[0];
    const float* pos_c = (const float*)d_in[1];
    const float* pos_f = (const float*)d_in[2];
    const int*   ei_c  = (const int*)d_in[3];
    const int*   ei_f  = (const int*)d_in[4];
    const float* We1 = (const float*)d_in[5];
    const float* be1 = (const float*)d_in[6];
    const float* Wn1 = (const float*)d_in[7];
    const float* bn1 = (const float*)d_in[8];
    const float* We2 = (const float*)d_in[9];
    const float* be2 = (const float*)d_in[10];
    const float* Wn2 = (const float*)d_in[11];
    const float* bn2 = (const float*)d_in[12];
    const float* WeS = (const float*)d_in[13];
    const float* beS = (const float*)d_in[14];
    const float* WnS = (const float*)d_in[15];
    const float* bnS = (const float*)d_in[16];
    const float* gamma = (const float*)d_in[17];
    const float* beta  = (const float*)d_in[18];

    char* w = (char*)d_ws;
    size_t o = 0;
    auto alloc = [&](size_t bytes) { void* p = w + o; o += (bytes + 255) & ~(size_t)255; return p; };
    int4*     knn_idx = (int4*)alloc((size_t)NF * sizeof(int4));
    float4*   knn_w   = (float4*)alloc((size_t)NF * sizeof(float4));
    ushort_t* RA      = (ushort_t*)alloc((size_t)NC * 512 * 2);   // also RE (aliased)
    ushort_t* Uf      = (ushort_t*)alloc((size_t)NF * 128 * 2);   // reused
    ushort_t* aggF    = (ushort_t*)alloc((size_t)NF * 128 * 2);   // reused
    ushort_t* agg1b   = (ushort_t*)alloc((size_t)NC * 64 * 2);
    ushort_t* xb      = (ushort_t*)alloc((size_t)NC * 128 * 2);
    ushort_t* WfA     = (ushort_t*)alloc(65536 * 2);
    ushort_t* WfE     = (ushort_t*)alloc(24576 * 2);
    ushort_t* WfSn    = (ushort_t*)alloc(16384 * 2);
    ushort_t* Wf1n    = (ushort_t*)alloc(12288 * 2);
    ushort_t* Wf2n    = (ushort_t*)alloc(16384 * 2);
    int*   cntF  = (int*)alloc((size_t)NF * sizeof(int));
    int*   baseF = (int*)alloc((size_t)(NF + 1) * sizeof(int));
    int*   cursF = (int*)alloc((size_t)NF * sizeof(int));
    int*   srtF  = (int*)alloc((size_t)EF * sizeof(int));
    int*   cntC  = (int*)alloc((size_t)NC * sizeof(int));
    int*   baseC = (int*)alloc((size_t)(NC + 1) * sizeof(int));
    int*   cursC = (int*)alloc((size_t)NC * sizeof(int));
    int*   srtC  = (int*)alloc((size_t)EC * sizeof(int));
    int*   cntG  = (int*)alloc((size_t)NCELL * sizeof(int));
    int*   baseG = (int*)alloc((size_t)(NCELL + 1) * sizeof(int));
    int*   cursG = (int*)alloc((size_t)NCELL * sizeof(int));
    float4* grecs = (float4*)alloc((size_t)NC * sizeof(float4));
    float* stats = (float*)alloc(256 * sizeof(float));
    ushort_t* RE = RA;               // RA dead once nodeSD starts
    float* outp = (float*)d_out;

    // 1. prep
    constexpr int PREP_TOTAL = NC * 128 + 65536 + 24576 + 16384 + 12288 + 16384
                             + NF + NC + NCELL + 256;
    prep_kernel<<<(PREP_TOTAL + 255) / 256, 256, 0, stream>>>(
        x, xb, WeS, WnS, We1, We2, Wn2, Wn1,
        WfA, WfE, WfSn, Wf1n, Wf2n, cntF, cntC, cntG, stats);

    // 2-4. merged counting sorts
    constexpr int SORT_ITEMS = EF + EC + NC;
    hist3_kernel<<<(SORT_ITEMS + 255) / 256, 256, 0, stream>>>(
        ei_f, ei_c, pos_c, cntF, cntC, cntG);
    scan3_kernel<<<3, 1024, 0, stream>>>(
        cntF, baseF, cursF, cntC, baseC, cursC, cntG, baseG, cursG);
    scatter3_kernel<<<(SORT_ITEMS + 255) / 256, 256, 0, stream>>>(
        ei_f, ei_c, pos_c, cursF, srtF, cursC, srtC, cursG, grecs);

    // 5. RA GEMM (bf16 out) + kNN
    gemmA_knn_kernel<<<768, 256, 0, stream>>>(
        xb, WfA, RA, pos_f, grecs, baseG, knn_idx, knn_w);

    // 6. aggS: fine skip agg (on-the-fly P/Q interp) + Uf_S + coarse agg1
    agg_kernel<512, true><<<NF / 4 + NC / 4, 256, 0, stream>>>(
        RA, knn_idx, knn_w, baseF, srtF, beS, aggF, Uf,
        baseC, srtC, be1, agg1b);

    // 7. nodeS (x_skip -> d_out) + node1 + fused gemmE (RE)
    nodeSD_kernel<<<320, 256, 0, stream>>>(
        aggF, WfSn, bnS, Uf, outp, xb, agg1b, Wf1n, bn1, WfE, RE);

    // 8. aggH: fine mpl2 agg (on-the-fly) + Uf_2
    agg_kernel<384, false><<<NF / 4, 256, 0, stream>>>(
        RE, knn_idx, knn_w, baseF, srtF, be2, aggF, Uf,
        nullptr, nullptr, nullptr, nullptr);

    // 9. nodeH: final MLP + residual + BN stats
    nodeH_kernel<<<256, 256, 0, stream>>>(aggF, Wf2n, bn2, Uf, outp, stats);

    // 10. BN + SELU
    bn_kernel<<<NF * 128 / 256, 256, 0, stream>>>(outp, stats, gamma, beta, NF);
}